// Round 1
// baseline (542.541 us; speedup 1.0000x reference)
//
#include <hip/hip_runtime.h>
#include <math.h>

constexpr int kB = 16, kC = 128, kHW = 4096, kL = 512, kND = 256, kG = 32;
constexpr float kEps = 1e-6f;

// ---------------- Kernel 1: GroupNorm statistics ----------------
// One block per (b, g). 4 channels x 4096 = 16384 contiguous floats.
__global__ __launch_bounds__(256) void gn_stats_k(const float* __restrict__ x,
                                                  float* __restrict__ stats) {
    int bg = blockIdx.x;
    const float4* p4 = (const float4*)(x + (size_t)bg * 4 * kHW);
    int tid = threadIdx.x;
    float s = 0.f, ss = 0.f;
    for (int i = tid; i < 4096; i += 256) {
        float4 v = p4[i];
        s  += (v.x + v.y) + (v.z + v.w);
        ss += (v.x * v.x + v.y * v.y) + (v.z * v.z + v.w * v.w);
    }
#pragma unroll
    for (int off = 1; off < 64; off <<= 1) {
        s  += __shfl_xor(s, off, 64);
        ss += __shfl_xor(ss, off, 64);
    }
    __shared__ float red[8];
    int wid = tid >> 6;
    if ((tid & 63) == 0) { red[wid] = s; red[wid + 4] = ss; }
    __syncthreads();
    if (tid == 0) {
        float S  = (red[0] + red[1]) + (red[2] + red[3]);
        float SS = (red[4] + red[5]) + (red[6] + red[7]);
        float mean = S * (1.f / 16384.f);
        float var  = SS * (1.f / 16384.f) - mean * mean;
        stats[bg * 2]     = mean;
        stats[bg * 2 + 1] = rsqrtf(var + kEps);
    }
}

// ---------------- Kernel 2: kv = silu(nd) @ nd_w^T + nd_b ----------------
// Block: 8 rows (l) of one batch, all 128 output channels.
__global__ __launch_bounds__(256) void kv_k(const float* __restrict__ nd,
                                            const float* __restrict__ nd_w,
                                            const float* __restrict__ nd_b,
                                            float* __restrict__ kv) {
    __shared__ float s_lds[8][256];    // silu(nd) tile
    __shared__ float w_lds[128][68];   // nd_w d-chunk, padded
    int b = blockIdx.y;
    int l0 = blockIdx.x * 8;
    int tid = threadIdx.x;
    const float4* ndp = (const float4*)(nd + ((size_t)b * kL + l0) * kND);
#pragma unroll
    for (int r = 0; r < 2; r++) {
        int idx = tid + r * 256;      // float4 index over 512
        int row = idx >> 6;           // 64 float4 per row
        int c4 = idx & 63;
        float4 v = ndp[row * 64 + c4];
        v.x = v.x / (1.f + __expf(-v.x));
        v.y = v.y / (1.f + __expf(-v.y));
        v.z = v.z / (1.f + __expf(-v.z));
        v.w = v.w / (1.f + __expf(-v.w));
        *(float4*)&s_lds[row][c4 * 4] = v;
    }
    float acc[4] = {0.f, 0.f, 0.f, 0.f};
    int lr = tid >> 5;    // row 0..7
    int oq = tid & 31;    // output lane
    for (int d0 = 0; d0 < kND; d0 += 64) {
        __syncthreads();
#pragma unroll
        for (int r = 0; r < 8; r++) {
            int idx = tid + r * 256;  // float4 over 2048 (128x64)
            int row = idx >> 4;       // 16 float4 per row
            int c4 = idx & 15;
            float4 v = ((const float4*)(nd_w + (size_t)row * kND + d0))[c4];
            *(float4*)&w_lds[row][c4 * 4] = v;
        }
        __syncthreads();
        for (int dd = 0; dd < 64; dd += 4) {
            float4 sv = *(const float4*)&s_lds[lr][d0 + dd];
#pragma unroll
            for (int j = 0; j < 4; j++) {
                float4 wv = *(const float4*)&w_lds[oq + 32 * j][dd];
                acc[j] += sv.x * wv.x + sv.y * wv.y + sv.z * wv.z + sv.w * wv.w;
            }
        }
    }
#pragma unroll
    for (int j = 0; j < 4; j++) {
        int o = oq + 32 * j;
        kv[((size_t)b * kL + l0 + lr) * kC + o] = acc[j] + nd_b[o];
    }
}

// ---------------- Kernel 3: q = (GN(x))^T @ q_w^T + q_b ----------------
// GroupNorm fused into the x-tile load; q written as (b, hw, c), coalesced
// via an LDS transpose.
__global__ __launch_bounds__(256) void qproj_k(const float* __restrict__ x,
                                               const float* __restrict__ stats,
                                               const float* __restrict__ gamma,
                                               const float* __restrict__ beta,
                                               const float* __restrict__ q_w,
                                               const float* __restrict__ q_b,
                                               float* __restrict__ q) {
    __shared__ float hn_lds[32][64];   // c-tile x n-tile (normalized x)
    __shared__ float qw_lds[128][33];  // q_w tile, padded
    __shared__ float q_out[64][129];   // transpose buffer, padded
    int b = blockIdx.y;
    int n0 = blockIdx.x * 64;
    int tid = threadIdx.x;
    int nn = tid & 63;
    int og = tid >> 6;   // wave id 0..3
    float acc[32];
#pragma unroll
    for (int j = 0; j < 32; j++) acc[j] = 0.f;

    for (int c0 = 0; c0 < kC; c0 += 32) {
        __syncthreads();
#pragma unroll
        for (int r = 0; r < 2; r++) {
            int idx = tid + r * 256;  // float4 over 512 (32x64)
            int row = idx >> 4;       // 16 float4 per row
            int c4 = idx & 15;
            int c = c0 + row;
            float4 v = ((const float4*)(x + ((size_t)b * kC + c) * kHW + n0))[c4];
            float mean = stats[(b * kG + (c >> 2)) * 2];
            float rstd = stats[(b * kG + (c >> 2)) * 2 + 1];
            float ga = gamma[c] * rstd;
            float be = beta[c] - mean * ga;
            v.x = v.x * ga + be; v.y = v.y * ga + be;
            v.z = v.z * ga + be; v.w = v.w * ga + be;
            *(float4*)&hn_lds[row][c4 * 4] = v;
        }
#pragma unroll
        for (int r = 0; r < 4; r++) {
            int idx = tid + r * 256;  // float4 over 1024 (128x32)
            int row = idx >> 3;       // 8 float4 per row
            int c4 = idx & 7;
            float4 v = ((const float4*)(q_w + (size_t)row * kC + c0))[c4];
            qw_lds[row][c4 * 4 + 0] = v.x;
            qw_lds[row][c4 * 4 + 1] = v.y;
            qw_lds[row][c4 * 4 + 2] = v.z;
            qw_lds[row][c4 * 4 + 3] = v.w;
        }
        __syncthreads();
        for (int cc = 0; cc < 32; cc++) {
            float h = hn_lds[cc][nn];
#pragma unroll
            for (int j = 0; j < 32; j++)
                acc[j] += h * qw_lds[og + 4 * j][cc];   // broadcast read
        }
    }
#pragma unroll
    for (int j = 0; j < 32; j++)
        q_out[nn][og + 4 * j] = acc[j];
    __syncthreads();
#pragma unroll
    for (int r2 = 0; r2 < 32; r2++) {
        int idx = tid + r2 * 256;     // 8192 = 64 x 128
        int row = idx >> 7;
        int o = idx & 127;
        q[((size_t)b * kHW + n0 + row) * kC + o] = q_out[row][o] + q_b[o];
    }
}

// ---------------- Kernel 4: attention + proj + residual ----------------
// Block: 32 positions of one batch. Thread = (n, 16-channel slice).
// Single-pass softmax (no max subtraction: |logit| << 1 by construction).
__global__ __launch_bounds__(256) void attn_k(const float* __restrict__ q,
                                              const float* __restrict__ kv,
                                              const float* __restrict__ proj_w,
                                              const float* __restrict__ proj_b,
                                              const float* __restrict__ x,
                                              float* __restrict__ out) {
    __shared__ float smem[12928];      // 51.7 KB
    float* kv_lds = smem;              // [64][132]  (aliased by pw_lds later)
    float* pw_lds = smem;              // [128][68]
    float* o_lds  = smem + 8704;       // [32][132]

    int b = blockIdx.y;
    int n0 = blockIdx.x * 32;
    int tid = threadIdx.x;
    int n = tid >> 3;   // 0..31
    int k = tid & 7;    // c-slice

    float qreg[16];
    {
        const float4* qp = (const float4*)(q + ((size_t)b * kHW + n0 + n) * kC + 16 * k);
#pragma unroll
        for (int j4 = 0; j4 < 4; j4++) {
            float4 v = qp[j4];
            qreg[4 * j4 + 0] = v.x; qreg[4 * j4 + 1] = v.y;
            qreg[4 * j4 + 2] = v.z; qreg[4 * j4 + 3] = v.w;
        }
    }
    float acc[16];
#pragma unroll
    for (int j = 0; j < 16; j++) acc[j] = 0.f;
    float ssum = 0.f;
    const float kScale = 0.08838834764831845f;  // 128^-0.5

    for (int l0 = 0; l0 < kL; l0 += 64) {
        __syncthreads();
        const float4* kvp = (const float4*)(kv + ((size_t)b * kL + l0) * kC);
#pragma unroll
        for (int r = 0; r < 8; r++) {
            int idx = tid + r * 256;  // float4 over 2048 (64x128)
            int row = idx >> 5;       // 32 float4 per row
            int c4 = idx & 31;
            float4 v = kvp[row * 32 + c4];
            *(float4*)&kv_lds[row * 132 + c4 * 4] = v;
        }
        __syncthreads();
        for (int l = 0; l < 64; l++) {
            const float* kvr = &kv_lds[l * 132 + 16 * k];
            float4 va = *(const float4*)(kvr + 0);
            float4 vb = *(const float4*)(kvr + 4);
            float4 vc = *(const float4*)(kvr + 8);
            float4 vd = *(const float4*)(kvr + 12);
            float dot = qreg[0] * va.x + qreg[1] * va.y + qreg[2] * va.z + qreg[3] * va.w
                      + qreg[4] * vb.x + qreg[5] * vb.y + qreg[6] * vb.z + qreg[7] * vb.w
                      + qreg[8] * vc.x + qreg[9] * vc.y + qreg[10] * vc.z + qreg[11] * vc.w
                      + qreg[12] * vd.x + qreg[13] * vd.y + qreg[14] * vd.z + qreg[15] * vd.w;
            dot += __shfl_xor(dot, 1, 64);
            dot += __shfl_xor(dot, 2, 64);
            dot += __shfl_xor(dot, 4, 64);
            float p = __expf(dot * kScale);
            ssum += p;
            acc[0]  += p * va.x; acc[1]  += p * va.y; acc[2]  += p * va.z; acc[3]  += p * va.w;
            acc[4]  += p * vb.x; acc[5]  += p * vb.y; acc[6]  += p * vb.z; acc[7]  += p * vb.w;
            acc[8]  += p * vc.x; acc[9]  += p * vc.y; acc[10] += p * vc.z; acc[11] += p * vc.w;
            acc[12] += p * vd.x; acc[13] += p * vd.y; acc[14] += p * vd.z; acc[15] += p * vd.w;
        }
    }

    float inv = 1.f / ssum;
#pragma unroll
    for (int j = 0; j < 16; j++)
        o_lds[n * 132 + 16 * k + j] = acc[j] * inv;

    // ---- projection + bias + residual ----
    float acc2[16];
#pragma unroll
    for (int j = 0; j < 16; j++) acc2[j] = 0.f;
    int oo = tid >> 5;   // 0..7
    int nn = tid & 31;
    for (int ch = 0; ch < 2; ch++) {
        __syncthreads();              // kv_lds reads done; safe to alias
#pragma unroll
        for (int r = 0; r < 8; r++) {
            int idx = tid + r * 256;  // float4 over 2048 (128x64)
            int row = idx >> 4;
            int c4 = idx & 15;
            float4 v = ((const float4*)(proj_w + (size_t)row * kC + ch * 64))[c4];
            *(float4*)&pw_lds[row * 68 + c4 * 4] = v;
        }
        __syncthreads();
        for (int cc = 0; cc < 64; cc++) {
            float h = o_lds[nn * 132 + ch * 64 + cc];
#pragma unroll
            for (int j = 0; j < 16; j++)
                acc2[j] += h * pw_lds[(oo + 8 * j) * 68 + cc];  // broadcast read
        }
    }
#pragma unroll
    for (int j = 0; j < 16; j++) {
        int o = oo + 8 * j;
        size_t oidx = ((size_t)b * kC + o) * kHW + n0 + nn;
        out[oidx] = acc2[j] + proj_b[o] + x[oidx];
    }
}

extern "C" void kernel_launch(void* const* d_in, const int* in_sizes, int n_in,
                              void* d_out, int out_size, void* d_ws, size_t ws_size,
                              hipStream_t stream) {
    const float* x      = (const float*)d_in[0];
    const float* nd     = (const float*)d_in[1];
    const float* gamma  = (const float*)d_in[2];
    const float* beta   = (const float*)d_in[3];
    const float* q_w    = (const float*)d_in[4];
    const float* q_b    = (const float*)d_in[5];
    const float* nd_w   = (const float*)d_in[6];
    const float* nd_b   = (const float*)d_in[7];
    const float* proj_w = (const float*)d_in[8];
    const float* proj_b = (const float*)d_in[9];
    float* out = (float*)d_out;

    float* stats = (float*)d_ws;                        // 1024 floats
    float* kv    = stats + 1024;                        // 16*512*128 = 1,048,576
    float* qbuf  = kv + (size_t)kB * kL * kC;           // 16*4096*128 = 8,388,608

    gn_stats_k<<<dim3(kB * kG), dim3(256), 0, stream>>>(x, stats);
    kv_k<<<dim3(kL / 8, kB), dim3(256), 0, stream>>>(nd, nd_w, nd_b, kv);
    qproj_k<<<dim3(kHW / 64, kB), dim3(256), 0, stream>>>(x, stats, gamma, beta, q_w, q_b, qbuf);
    attn_k<<<dim3(kHW / 32, kB), dim3(256), 0, stream>>>(qbuf, kv, proj_w, proj_b, x, out);
}

// Round 2
// 167.119 us; speedup vs baseline: 3.2464x; 3.2464x over previous
//
#include <hip/hip_runtime.h>
#include <math.h>

constexpr int kB = 16, kC = 128, kHW = 4096, kL = 512, kND = 256, kG = 32;
constexpr float kEps = 1e-6f;
constexpr float kScale = 0.08838834764831845f;  // 128^-0.5

typedef short sv8 __attribute__((ext_vector_type(8)));
typedef float f32x16 __attribute__((ext_vector_type(16)));

static __device__ __forceinline__ unsigned short f2bf(float f) {
    unsigned int u = __builtin_bit_cast(unsigned int, f);
    u += 0x7fffu + ((u >> 16) & 1u);
    return (unsigned short)(u >> 16);
}
static __device__ __forceinline__ float bf2f(unsigned short s) {
    unsigned int u = ((unsigned int)s) << 16;
    return __builtin_bit_cast(float, u);
}

// ---------------- Kernel 1: GroupNorm statistics ----------------
__global__ __launch_bounds__(256) void gn_stats_k(const float* __restrict__ x,
                                                  float* __restrict__ stats) {
    int bg = blockIdx.x;
    const float4* p4 = (const float4*)(x + (size_t)bg * 4 * kHW);
    int tid = threadIdx.x;
    float s = 0.f, ss = 0.f;
    for (int i = tid; i < 4096; i += 256) {
        float4 v = p4[i];
        s  += (v.x + v.y) + (v.z + v.w);
        ss += (v.x * v.x + v.y * v.y) + (v.z * v.z + v.w * v.w);
    }
#pragma unroll
    for (int off = 1; off < 64; off <<= 1) {
        s  += __shfl_xor(s, off, 64);
        ss += __shfl_xor(ss, off, 64);
    }
    __shared__ float red[8];
    int wid = tid >> 6;
    if ((tid & 63) == 0) { red[wid] = s; red[wid + 4] = ss; }
    __syncthreads();
    if (tid == 0) {
        float S  = (red[0] + red[1]) + (red[2] + red[3]);
        float SS = (red[4] + red[5]) + (red[6] + red[7]);
        float mean = S * (1.f / 16384.f);
        float var  = SS * (1.f / 16384.f) - mean * mean;
        stats[bg * 2]     = mean;
        stats[bg * 2 + 1] = rsqrtf(var + kEps);
    }
}

// ---------------- Kernel 1b: proj_w -> bf16 ----------------
__global__ __launch_bounds__(256) void prep_k(const float* __restrict__ w,
                                              unsigned short* __restrict__ wb) {
    int i = (blockIdx.x * 256 + threadIdx.x) * 4;
    float4 v = *(const float4*)(w + i);
    wb[i + 0] = f2bf(v.x); wb[i + 1] = f2bf(v.y);
    wb[i + 2] = f2bf(v.z); wb[i + 3] = f2bf(v.w);
}

// ---------------- Kernel 2: kv = silu(nd) @ nd_w^T + nd_b (bf16 + bf16^T) ----
__global__ __launch_bounds__(256) void kv_k(const float* __restrict__ nd,
                                            const float* __restrict__ nd_w,
                                            const float* __restrict__ nd_b,
                                            unsigned short* __restrict__ kv_bf,
                                            unsigned short* __restrict__ kvT_bf) {
    __shared__ float s_lds[8][256];
    __shared__ float w_lds[128][68];
    __shared__ float t_lds[8][129];
    int b = blockIdx.y;
    int l0 = blockIdx.x * 8;
    int tid = threadIdx.x;
    const float4* ndp = (const float4*)(nd + ((size_t)b * kL + l0) * kND);
#pragma unroll
    for (int r = 0; r < 2; r++) {
        int idx = tid + r * 256;
        int row = idx >> 6;
        int c4 = idx & 63;
        float4 v = ndp[row * 64 + c4];
        v.x = v.x / (1.f + __expf(-v.x));
        v.y = v.y / (1.f + __expf(-v.y));
        v.z = v.z / (1.f + __expf(-v.z));
        v.w = v.w / (1.f + __expf(-v.w));
        *(float4*)&s_lds[row][c4 * 4] = v;
    }
    float acc[4] = {0.f, 0.f, 0.f, 0.f};
    int lr = tid >> 5;
    int oq = tid & 31;
    for (int d0 = 0; d0 < kND; d0 += 64) {
        __syncthreads();
#pragma unroll
        for (int r = 0; r < 8; r++) {
            int idx = tid + r * 256;
            int row = idx >> 4;
            int c4 = idx & 15;
            float4 v = ((const float4*)(nd_w + (size_t)row * kND + d0))[c4];
            *(float4*)&w_lds[row][c4 * 4] = v;
        }
        __syncthreads();
        for (int dd = 0; dd < 64; dd += 4) {
            float4 sv = *(const float4*)&s_lds[lr][d0 + dd];
#pragma unroll
            for (int j = 0; j < 4; j++) {
                float4 wv = *(const float4*)&w_lds[oq + 32 * j][dd];
                acc[j] += sv.x * wv.x + sv.y * wv.y + sv.z * wv.z + sv.w * wv.w;
            }
        }
    }
#pragma unroll
    for (int j = 0; j < 4; j++) {
        int o = oq + 32 * j;
        float vout = acc[j] + nd_b[o];
        kv_bf[((size_t)b * kL + l0 + lr) * kC + o] = f2bf(vout);
        t_lds[lr][o] = vout;
    }
    __syncthreads();
    {
        int o = tid >> 1, lh = (tid & 1) * 4;
        unsigned long long pk = 0;
#pragma unroll
        for (int i = 0; i < 4; i++)
            pk |= (unsigned long long)f2bf(t_lds[lh + i][o]) << (16 * i);
        *(unsigned long long*)(kvT_bf + ((size_t)b * kC + o) * kL + l0 + lh) = pk;
    }
}

// ---------------- Kernel 3: q = (GN(x))^T @ q_w^T + q_b, scaled, bf16 -------
__global__ __launch_bounds__(256) void qproj_k(const float* __restrict__ x,
                                               const float* __restrict__ stats,
                                               const float* __restrict__ gamma,
                                               const float* __restrict__ beta,
                                               const float* __restrict__ q_w,
                                               const float* __restrict__ q_b,
                                               unsigned short* __restrict__ q_bf) {
    __shared__ float hn_lds[32][64];
    __shared__ float qw_lds[128][33];
    __shared__ float q_out[64][129];
    int b = blockIdx.y;
    int n0 = blockIdx.x * 64;
    int tid = threadIdx.x;
    int nn = tid & 63;
    int og = tid >> 6;
    float acc[32];
#pragma unroll
    for (int j = 0; j < 32; j++) acc[j] = 0.f;

    for (int c0 = 0; c0 < kC; c0 += 32) {
        __syncthreads();
#pragma unroll
        for (int r = 0; r < 2; r++) {
            int idx = tid + r * 256;
            int row = idx >> 4;
            int c4 = idx & 15;
            int c = c0 + row;
            float4 v = ((const float4*)(x + ((size_t)b * kC + c) * kHW + n0))[c4];
            float mean = stats[(b * kG + (c >> 2)) * 2];
            float rstd = stats[(b * kG + (c >> 2)) * 2 + 1];
            float ga = gamma[c] * rstd;
            float be = beta[c] - mean * ga;
            v.x = v.x * ga + be; v.y = v.y * ga + be;
            v.z = v.z * ga + be; v.w = v.w * ga + be;
            *(float4*)&hn_lds[row][c4 * 4] = v;
        }
#pragma unroll
        for (int r = 0; r < 4; r++) {
            int idx = tid + r * 256;
            int row = idx >> 3;
            int c4 = idx & 7;
            float4 v = ((const float4*)(q_w + (size_t)row * kC + c0))[c4];
            qw_lds[row][c4 * 4 + 0] = v.x;
            qw_lds[row][c4 * 4 + 1] = v.y;
            qw_lds[row][c4 * 4 + 2] = v.z;
            qw_lds[row][c4 * 4 + 3] = v.w;
        }
        __syncthreads();
        for (int cc = 0; cc < 32; cc++) {
            float h = hn_lds[cc][nn];
#pragma unroll
            for (int j = 0; j < 32; j++)
                acc[j] += h * qw_lds[og + 4 * j][cc];
        }
    }
#pragma unroll
    for (int j = 0; j < 32; j++)
        q_out[nn][og + 4 * j] = acc[j];
    __syncthreads();
#pragma unroll
    for (int r2 = 0; r2 < 32; r2++) {
        int idx = tid + r2 * 256;
        int row = idx >> 7;
        int o = idx & 127;
        q_bf[((size_t)b * kHW + n0 + row) * kC + o] = f2bf((q_out[row][o] + q_b[o]) * kScale);
    }
}

// ---------------- Kernel 4: MFMA attention + proj + residual ----------------
// Block: 128 Q-rows x 1 batch, 4 waves x 32 rows. grid 512 = 2 blocks/CU.
__global__ __launch_bounds__(256, 2) void attn_k(
    const unsigned short* __restrict__ qb,    // [B][HW][C] bf16, pre-scaled
    const unsigned short* __restrict__ kvb,   // [B][L][C] bf16
    const unsigned short* __restrict__ kvtb,  // [B][C][L] bf16
    const unsigned short* __restrict__ pwb,   // [C][C] bf16 (o-major)
    const float* __restrict__ proj_b,
    const float* __restrict__ x,
    float* __restrict__ out)
{
    __shared__ __align__(16) unsigned short smem[27136];  // 54272 B
    unsigned short* kv_lds  = smem;            // [64][136]
    unsigned short* kvt_lds = smem + 8704;     // [128][72]
    unsigned short* p_lds   = smem + 17920;    // 4 x [32][72]
    unsigned short* o_lds   = smem;            // [128][136] (aliases kv/kvt)

    const int b = blockIdx.y;
    const int n0 = blockIdx.x * 128;
    const int tid = threadIdx.x;
    const int wave = tid >> 6;
    const int lane = tid & 63;
    const int lrow = lane & 31;
    const int hi = lane >> 5;

    // Q A-fragments: row = lane&31, k = 8*hi + j, 8 chunks of K=16
    sv8 qa[8];
    {
        const unsigned short* qrow =
            qb + ((size_t)b * kHW + n0 + wave * 32 + lrow) * kC + hi * 8;
#pragma unroll
        for (int kc = 0; kc < 8; kc++)
            qa[kc] = *(const sv8*)(qrow + kc * 16);
    }

    f32x16 oacc[4];
#pragma unroll
    for (int ct = 0; ct < 4; ct++)
#pragma unroll
        for (int r = 0; r < 16; r++) oacc[ct][r] = 0.f;
    float rsum[16];
#pragma unroll
    for (int r = 0; r < 16; r++) rsum[r] = 0.f;

    unsigned short* myp = p_lds + wave * 2304;  // [32][72]

    for (int l0 = 0; l0 < kL; l0 += 64) {
        __syncthreads();
        {   // stage kv row-major [64][136] and kv^T [128][72]
            const uint4* g = (const uint4*)(kvb + ((size_t)b * kL + l0) * kC);
#pragma unroll
            for (int r = 0; r < 4; r++) {
                int idx = tid + r * 256;
                int row = idx >> 4, c8 = idx & 15;
                *(uint4*)(kv_lds + row * 136 + c8 * 8) = g[idx];
            }
            const uint4* gt = (const uint4*)(kvtb + (size_t)b * kC * kL + l0);
#pragma unroll
            for (int r = 0; r < 4; r++) {
                int idx = tid + r * 256;
                int row = idx >> 3, c8 = idx & 7;
                *(uint4*)(kvt_lds + row * 72 + c8 * 8) = gt[row * 64 + c8];
            }
        }
        __syncthreads();

        // QK^T: S[n][l], 2 l-subtiles of 32
#pragma unroll
        for (int ls = 0; ls < 2; ls++) {
            f32x16 s;
#pragma unroll
            for (int r = 0; r < 16; r++) s[r] = 0.f;
            const unsigned short* brow = kv_lds + (ls * 32 + lrow) * 136 + hi * 8;
#pragma unroll
            for (int kc = 0; kc < 8; kc++)
                s = __builtin_amdgcn_mfma_f32_32x32x16_bf16(
                        qa[kc], *(const sv8*)(brow + kc * 16), s, 0, 0, 0);
            // exp (max-free: |logit| << 1), rowsum, P -> LDS (bf16)
#pragma unroll
            for (int r = 0; r < 16; r++) {
                float p = __expf(s[r]);
                rsum[r] += p;
                int n = (r & 3) + 8 * (r >> 2) + 4 * hi;
                myp[n * 72 + ls * 32 + lrow] = f2bf(p);
            }
        }
        // PV: A = P (re-read in A layout), B = kv^T
        sv8 pa[4];
#pragma unroll
        for (int kk = 0; kk < 4; kk++)
            pa[kk] = *(const sv8*)(myp + lrow * 72 + kk * 16 + hi * 8);
#pragma unroll
        for (int ct = 0; ct < 4; ct++) {
            const unsigned short* brow = kvt_lds + (ct * 32 + lrow) * 72 + hi * 8;
#pragma unroll
            for (int kk = 0; kk < 4; kk++)
                oacc[ct] = __builtin_amdgcn_mfma_f32_32x32x16_bf16(
                               pa[kk], *(const sv8*)(brow + kk * 16), oacc[ct], 0, 0, 0);
        }
    }

    // softmax denominators: reduce across the 32 l-columns
#pragma unroll
    for (int r = 0; r < 16; r++) {
        float v = rsum[r];
        v += __shfl_xor(v, 1, 64);
        v += __shfl_xor(v, 2, 64);
        v += __shfl_xor(v, 4, 64);
        v += __shfl_xor(v, 8, 64);
        v += __shfl_xor(v, 16, 64);
        rsum[r] = 1.f / v;
    }

    __syncthreads();  // all kv/kvt/p reads done; o_lds aliases
    // normalized O -> o_lds bf16 [128 n][136 c]  (per-wave row-disjoint)
#pragma unroll
    for (int ct = 0; ct < 4; ct++)
#pragma unroll
        for (int r = 0; r < 16; r++) {
            int n = wave * 32 + (r & 3) + 8 * (r >> 2) + 4 * hi;
            o_lds[n * 136 + ct * 32 + lrow] = f2bf(oacc[ct][r] * rsum[r]);
        }
    // proj: D[n][o] = O[n][c] * pw[o][c]
    sv8 oa[8];
    {
        const unsigned short* orow = o_lds + (wave * 32 + lrow) * 136 + hi * 8;
#pragma unroll
        for (int kc = 0; kc < 8; kc++) oa[kc] = *(const sv8*)(orow + kc * 16);
    }
    f32x16 dacc[4];
#pragma unroll
    for (int ot = 0; ot < 4; ot++)
#pragma unroll
        for (int r = 0; r < 16; r++) dacc[ot][r] = 0.f;
#pragma unroll
    for (int ot = 0; ot < 4; ot++) {
        const unsigned short* brow = pwb + (ot * 32 + lrow) * kC + hi * 8;
#pragma unroll
        for (int kc = 0; kc < 8; kc++)
            dacc[ot] = __builtin_amdgcn_mfma_f32_32x32x16_bf16(
                           oa[kc], *(const sv8*)(brow + kc * 16), dacc[ot], 0, 0, 0);
    }
    // D -> o_lds bf16 [128 n][136 o] (own rows only; reads already in regs)
#pragma unroll
    for (int ot = 0; ot < 4; ot++)
#pragma unroll
        for (int r = 0; r < 16; r++) {
            int n = wave * 32 + (r & 3) + 8 * (r >> 2) + 4 * hi;
            o_lds[n * 136 + ot * 32 + lrow] = f2bf(dacc[ot][r]);
        }
    __syncthreads();
    // epilogue: out[b][o][n0+n] = D[n][o] + proj_b[o] + x  (coalesced)
#pragma unroll 4
    for (int it = 0; it < 64; it++) {
        int idx = it * 256 + tid;
        int o = idx >> 7, n = idx & 127;
        size_t gi = ((size_t)b * kC + o) * kHW + n0 + n;
        out[gi] = bf2f(o_lds[n * 136 + o]) + proj_b[o] + x[gi];
    }
}

extern "C" void kernel_launch(void* const* d_in, const int* in_sizes, int n_in,
                              void* d_out, int out_size, void* d_ws, size_t ws_size,
                              hipStream_t stream) {
    const float* x      = (const float*)d_in[0];
    const float* nd     = (const float*)d_in[1];
    const float* gamma  = (const float*)d_in[2];
    const float* beta   = (const float*)d_in[3];
    const float* q_w    = (const float*)d_in[4];
    const float* q_b    = (const float*)d_in[5];
    const float* nd_w   = (const float*)d_in[6];
    const float* nd_b   = (const float*)d_in[7];
    const float* proj_w = (const float*)d_in[8];
    const float* proj_b = (const float*)d_in[9];
    float* out = (float*)d_out;

    float* stats          = (float*)d_ws;                  // 1024 f32
    unsigned short* pwb   = (unsigned short*)(stats + 1024);       // 16384
    unsigned short* kv_bf = pwb + 16384;                   // 1,048,576
    unsigned short* kvT_bf = kv_bf + (size_t)kB * kL * kC; // 1,048,576
    unsigned short* q_bf  = kvT_bf + (size_t)kB * kL * kC; // 8,388,608

    gn_stats_k<<<dim3(kB * kG), dim3(256), 0, stream>>>(x, stats);
    prep_k<<<dim3(16), dim3(256), 0, stream>>>(proj_w, pwb);
    kv_k<<<dim3(kL / 8, kB), dim3(256), 0, stream>>>(nd, nd_w, nd_b, kv_bf, kvT_bf);
    qproj_k<<<dim3(kHW / 64, kB), dim3(256), 0, stream>>>(x, stats, gamma, beta, q_w, q_b, q_bf);
    attn_k<<<dim3(kHW / 128, kB), dim3(256), 0, stream>>>(q_bf, kv_bf, kvT_bf, pwb,
                                                          proj_b, x, out);
}

// Round 3
// 99.976 us; speedup vs baseline: 5.4267x; 1.6716x over previous
//
#include <hip/hip_runtime.h>
#include <math.h>

constexpr int kB = 16, kC = 128, kHW = 4096, kL = 512, kND = 256, kG = 32;
constexpr float kEps = 1e-6f;
constexpr float kScale = 0.08838834764831845f;  // 128^-0.5

typedef short sv8 __attribute__((ext_vector_type(8)));
typedef float f32x16 __attribute__((ext_vector_type(16)));

static __device__ __forceinline__ unsigned short f2bf(float f) {
    unsigned int u = __builtin_bit_cast(unsigned int, f);
    u += 0x7fffu + ((u >> 16) & 1u);
    return (unsigned short)(u >> 16);
}
static __device__ __forceinline__ float bf2f(unsigned short s) {
    unsigned int u = ((unsigned int)s) << 16;
    return __builtin_bit_cast(float, u);
}

// ---------------- Kernel 1: GroupNorm statistics ----------------
__global__ __launch_bounds__(256) void gn_stats_k(const float* __restrict__ x,
                                                  float* __restrict__ stats) {
    int bg = blockIdx.x;
    const float4* p4 = (const float4*)(x + (size_t)bg * 4 * kHW);
    int tid = threadIdx.x;
    float s = 0.f, ss = 0.f;
    for (int i = tid; i < 4096; i += 256) {
        float4 v = p4[i];
        s  += (v.x + v.y) + (v.z + v.w);
        ss += (v.x * v.x + v.y * v.y) + (v.z * v.z + v.w * v.w);
    }
#pragma unroll
    for (int off = 1; off < 64; off <<= 1) {
        s  += __shfl_xor(s, off, 64);
        ss += __shfl_xor(ss, off, 64);
    }
    __shared__ float red[8];
    int wid = tid >> 6;
    if ((tid & 63) == 0) { red[wid] = s; red[wid + 4] = ss; }
    __syncthreads();
    if (tid == 0) {
        float S  = (red[0] + red[1]) + (red[2] + red[3]);
        float SS = (red[4] + red[5]) + (red[6] + red[7]);
        float mean = S * (1.f / 16384.f);
        float var  = SS * (1.f / 16384.f) - mean * mean;
        stats[bg * 2]     = mean;
        stats[bg * 2 + 1] = rsqrtf(var + kEps);
    }
}

// ---------------- Kernel 1b: proj_w -> bf16 ----------------
__global__ __launch_bounds__(256) void prep_k(const float* __restrict__ w,
                                              unsigned short* __restrict__ wb) {
    int i = (blockIdx.x * 256 + threadIdx.x) * 4;
    float4 v = *(const float4*)(w + i);
    wb[i + 0] = f2bf(v.x); wb[i + 1] = f2bf(v.y);
    wb[i + 2] = f2bf(v.z); wb[i + 3] = f2bf(v.w);
}

// ---------------- Kernel 2: kv = silu(nd) @ nd_w^T + nd_b (bf16 + bf16^T) ----
__global__ __launch_bounds__(256) void kv_k(const float* __restrict__ nd,
                                            const float* __restrict__ nd_w,
                                            const float* __restrict__ nd_b,
                                            unsigned short* __restrict__ kv_bf,
                                            unsigned short* __restrict__ kvT_bf) {
    __shared__ float s_lds[8][256];
    __shared__ float w_lds[128][68];
    __shared__ float t_lds[8][129];
    int b = blockIdx.y;
    int l0 = blockIdx.x * 8;
    int tid = threadIdx.x;
    const float4* ndp = (const float4*)(nd + ((size_t)b * kL + l0) * kND);
#pragma unroll
    for (int r = 0; r < 2; r++) {
        int idx = tid + r * 256;
        int row = idx >> 6;
        int c4 = idx & 63;
        float4 v = ndp[row * 64 + c4];
        v.x = v.x / (1.f + __expf(-v.x));
        v.y = v.y / (1.f + __expf(-v.y));
        v.z = v.z / (1.f + __expf(-v.z));
        v.w = v.w / (1.f + __expf(-v.w));
        *(float4*)&s_lds[row][c4 * 4] = v;
    }
    float acc[4] = {0.f, 0.f, 0.f, 0.f};
    int lr = tid >> 5;
    int oq = tid & 31;
    for (int d0 = 0; d0 < kND; d0 += 64) {
        __syncthreads();
#pragma unroll
        for (int r = 0; r < 8; r++) {
            int idx = tid + r * 256;
            int row = idx >> 4;
            int c4 = idx & 15;
            float4 v = ((const float4*)(nd_w + (size_t)row * kND + d0))[c4];
            *(float4*)&w_lds[row][c4 * 4] = v;
        }
        __syncthreads();
        for (int dd = 0; dd < 64; dd += 4) {
            float4 sv = *(const float4*)&s_lds[lr][d0 + dd];
#pragma unroll
            for (int j = 0; j < 4; j++) {
                float4 wv = *(const float4*)&w_lds[oq + 32 * j][dd];
                acc[j] += sv.x * wv.x + sv.y * wv.y + sv.z * wv.z + sv.w * wv.w;
            }
        }
    }
#pragma unroll
    for (int j = 0; j < 4; j++) {
        int o = oq + 32 * j;
        float vout = acc[j] + nd_b[o];
        kv_bf[((size_t)b * kL + l0 + lr) * kC + o] = f2bf(vout);
        t_lds[lr][o] = vout;
    }
    __syncthreads();
    {
        int o = tid >> 1, lh = (tid & 1) * 4;
        unsigned long long pk = 0;
#pragma unroll
        for (int i = 0; i < 4; i++)
            pk |= (unsigned long long)f2bf(t_lds[lh + i][o]) << (16 * i);
        *(unsigned long long*)(kvT_bf + ((size_t)b * kC + o) * kL + l0 + lh) = pk;
    }
}

// ---------------- Kernel 3: q = (GN(x))^T @ q_w^T + q_b  (bf16 MFMA) -------
// Block: 128 n-rows x 128 o, one batch. A-fragments loaded global->reg with
// GN fused (coalesced per-half-wave); q_w staged bf16 in LDS; D transposed
// through the same LDS buffer for coalesced bf16 stores.
__global__ __launch_bounds__(256) void qproj_k(const float* __restrict__ x,
                                               const float* __restrict__ stats,
                                               const float* __restrict__ gamma,
                                               const float* __restrict__ beta,
                                               const float* __restrict__ q_w,
                                               const float* __restrict__ q_b,
                                               unsigned short* __restrict__ q_bf) {
    __shared__ __align__(16) unsigned short smem[17408];  // [128][136] bf16
    __shared__ float gab[256];                            // ga[128], be[128]
    const int b = blockIdx.y;
    const int n0 = blockIdx.x * 128;
    const int tid = threadIdx.x;
    const int wave = tid >> 6, lane = tid & 63;
    const int lrow = lane & 31, hi = lane >> 5;

    if (tid < 128) {
        float mean = stats[(b * kG + (tid >> 2)) * 2];
        float rstd = stats[(b * kG + (tid >> 2)) * 2 + 1];
        float ga = gamma[tid] * rstd;
        gab[tid] = ga;
        gab[128 + tid] = beta[tid] - mean * ga;
    }
    // stage q_w as bf16 [o][c], padded stride 136
#pragma unroll
    for (int r = 0; r < 16; r++) {
        int idx = tid + r * 256;            // 4096 float4 = 128x32
        int row = idx >> 5, c4 = idx & 31;
        float4 v = ((const float4*)q_w)[idx];
        unsigned int lo = (unsigned int)f2bf(v.x) | ((unsigned int)f2bf(v.y) << 16);
        unsigned int h2 = (unsigned int)f2bf(v.z) | ((unsigned int)f2bf(v.w) << 16);
        *(uint2*)&smem[row * 136 + c4 * 4] = make_uint2(lo, h2);
    }
    __syncthreads();

    // A fragments: hn[n][c] with GN fused, straight from global
    sv8 qa[8];
    {
        const float* xp = x + (size_t)b * kC * kHW + n0 + wave * 32 + lrow;
#pragma unroll
        for (int kc = 0; kc < 8; kc++) {
            int cb = kc * 16 + hi * 8;
            float4 g0 = *(const float4*)&gab[cb];
            float4 g1 = *(const float4*)&gab[cb + 4];
            float4 e0 = *(const float4*)&gab[128 + cb];
            float4 e1 = *(const float4*)&gab[128 + cb + 4];
            sv8 a;
            a[0] = (short)f2bf(xp[(size_t)(cb + 0) * kHW] * g0.x + e0.x);
            a[1] = (short)f2bf(xp[(size_t)(cb + 1) * kHW] * g0.y + e0.y);
            a[2] = (short)f2bf(xp[(size_t)(cb + 2) * kHW] * g0.z + e0.z);
            a[3] = (short)f2bf(xp[(size_t)(cb + 3) * kHW] * g0.w + e0.w);
            a[4] = (short)f2bf(xp[(size_t)(cb + 4) * kHW] * g1.x + e1.x);
            a[5] = (short)f2bf(xp[(size_t)(cb + 5) * kHW] * g1.y + e1.y);
            a[6] = (short)f2bf(xp[(size_t)(cb + 6) * kHW] * g1.z + e1.z);
            a[7] = (short)f2bf(xp[(size_t)(cb + 7) * kHW] * g1.w + e1.w);
            qa[kc] = a;
        }
    }

    f32x16 dacc[4];
#pragma unroll
    for (int ot = 0; ot < 4; ot++)
#pragma unroll
        for (int r = 0; r < 16; r++) dacc[ot][r] = 0.f;
#pragma unroll
    for (int ot = 0; ot < 4; ot++) {
        const unsigned short* brow = smem + (ot * 32 + lrow) * 136 + hi * 8;
#pragma unroll
        for (int kc = 0; kc < 8; kc++)
            dacc[ot] = __builtin_amdgcn_mfma_f32_32x32x16_bf16(
                           qa[kc], *(const sv8*)(brow + kc * 16), dacc[ot], 0, 0, 0);
    }
    __syncthreads();   // all B-reads done; reuse smem as q[n][o] transpose

#pragma unroll
    for (int ot = 0; ot < 4; ot++) {
        int o = ot * 32 + lrow;
        float qb = q_b[o];
#pragma unroll
        for (int r = 0; r < 16; r++) {
            int n_loc = wave * 32 + (r & 3) + 8 * (r >> 2) + 4 * hi;
            smem[n_loc * 136 + o] = f2bf((dacc[ot][r] + qb) * kScale);
        }
    }
    __syncthreads();
#pragma unroll
    for (int r = 0; r < 8; r++) {
        int idx = tid + r * 256;            // 2048 uint4 = 128 rows x 16
        int n = idx >> 4, ch = idx & 15;
        *(uint4*)(q_bf + ((size_t)b * kHW + n0 + n) * kC + ch * 8) =
            *(const uint4*)&smem[n * 136 + ch * 8];
    }
}

// ---------------- Kernel 4: MFMA attention + proj + residual ----------------
// Block: 128 Q-rows x 1 batch, 4 waves x 32 rows. grid 512 = 2 blocks/CU.
__global__ __launch_bounds__(256, 2) void attn_k(
    const unsigned short* __restrict__ qb,    // [B][HW][C] bf16, pre-scaled
    const unsigned short* __restrict__ kvb,   // [B][L][C] bf16
    const unsigned short* __restrict__ kvtb,  // [B][C][L] bf16
    const unsigned short* __restrict__ pwb,   // [C][C] bf16 (o-major)
    const float* __restrict__ proj_b,
    const float* __restrict__ x,
    float* __restrict__ out)
{
    __shared__ __align__(16) unsigned short smem[27136];  // 54272 B
    unsigned short* kv_lds  = smem;            // [64][136]
    unsigned short* kvt_lds = smem + 8704;     // [128][72]
    unsigned short* p_lds   = smem + 17920;    // 4 x [32][72]
    unsigned short* o_lds   = smem;            // [128][136] (aliases kv/kvt)

    const int b = blockIdx.y;
    const int n0 = blockIdx.x * 128;
    const int tid = threadIdx.x;
    const int wave = tid >> 6;
    const int lane = tid & 63;
    const int lrow = lane & 31;
    const int hi = lane >> 5;

    // Q A-fragments: row = lane&31, k = 8*hi + j, 8 chunks of K=16
    sv8 qa[8];
    {
        const unsigned short* qrow =
            qb + ((size_t)b * kHW + n0 + wave * 32 + lrow) * kC + hi * 8;
#pragma unroll
        for (int kc = 0; kc < 8; kc++)
            qa[kc] = *(const sv8*)(qrow + kc * 16);
    }

    f32x16 oacc[4];
#pragma unroll
    for (int ct = 0; ct < 4; ct++)
#pragma unroll
        for (int r = 0; r < 16; r++) oacc[ct][r] = 0.f;
    float rsum[16];
#pragma unroll
    for (int r = 0; r < 16; r++) rsum[r] = 0.f;

    unsigned short* myp = p_lds + wave * 2304;  // [32][72]

    for (int l0 = 0; l0 < kL; l0 += 64) {
        __syncthreads();
        {   // stage kv row-major [64][136] and kv^T [128][72]
            const uint4* g = (const uint4*)(kvb + ((size_t)b * kL + l0) * kC);
#pragma unroll
            for (int r = 0; r < 4; r++) {
                int idx = tid + r * 256;
                int row = idx >> 4, c8 = idx & 15;
                *(uint4*)(kv_lds + row * 136 + c8 * 8) = g[idx];
            }
            const uint4* gt = (const uint4*)(kvtb + (size_t)b * kC * kL + l0);
#pragma unroll
            for (int r = 0; r < 4; r++) {
                int idx = tid + r * 256;
                int row = idx >> 3, c8 = idx & 7;
                *(uint4*)(kvt_lds + row * 72 + c8 * 8) = gt[row * 64 + c8];
            }
        }
        __syncthreads();

        // QK^T: S[n][l], 2 l-subtiles of 32
#pragma unroll
        for (int ls = 0; ls < 2; ls++) {
            f32x16 s;
#pragma unroll
            for (int r = 0; r < 16; r++) s[r] = 0.f;
            const unsigned short* brow = kv_lds + (ls * 32 + lrow) * 136 + hi * 8;
#pragma unroll
            for (int kc = 0; kc < 8; kc++)
                s = __builtin_amdgcn_mfma_f32_32x32x16_bf16(
                        qa[kc], *(const sv8*)(brow + kc * 16), s, 0, 0, 0);
            // exp (max-free: |logit| << 1), rowsum, P -> LDS (bf16)
#pragma unroll
            for (int r = 0; r < 16; r++) {
                float p = __expf(s[r]);
                rsum[r] += p;
                int n = (r & 3) + 8 * (r >> 2) + 4 * hi;
                myp[n * 72 + ls * 32 + lrow] = f2bf(p);
            }
        }
        // PV: A = P (re-read in A layout), B = kv^T
        sv8 pa[4];
#pragma unroll
        for (int kk = 0; kk < 4; kk++)
            pa[kk] = *(const sv8*)(myp + lrow * 72 + kk * 16 + hi * 8);
#pragma unroll
        for (int ct = 0; ct < 4; ct++) {
            const unsigned short* brow = kvt_lds + (ct * 32 + lrow) * 72 + hi * 8;
#pragma unroll
            for (int kk = 0; kk < 4; kk++)
                oacc[ct] = __builtin_amdgcn_mfma_f32_32x32x16_bf16(
                               pa[kk], *(const sv8*)(brow + kk * 16), oacc[ct], 0, 0, 0);
        }
    }

    // softmax denominators: reduce across the 32 l-columns
#pragma unroll
    for (int r = 0; r < 16; r++) {
        float v = rsum[r];
        v += __shfl_xor(v, 1, 64);
        v += __shfl_xor(v, 2, 64);
        v += __shfl_xor(v, 4, 64);
        v += __shfl_xor(v, 8, 64);
        v += __shfl_xor(v, 16, 64);
        rsum[r] = 1.f / v;
    }

    __syncthreads();  // all kv/kvt/p reads done; o_lds aliases
    // normalized O -> o_lds bf16 [128 n][136 c]  (per-wave row-disjoint)
#pragma unroll
    for (int ct = 0; ct < 4; ct++)
#pragma unroll
        for (int r = 0; r < 16; r++) {
            int n = wave * 32 + (r & 3) + 8 * (r >> 2) + 4 * hi;
            o_lds[n * 136 + ct * 32 + lrow] = f2bf(oacc[ct][r] * rsum[r]);
        }
    // proj: D[n][o] = O[n][c] * pw[o][c]
    sv8 oa[8];
    {
        const unsigned short* orow = o_lds + (wave * 32 + lrow) * 136 + hi * 8;
#pragma unroll
        for (int kc = 0; kc < 8; kc++) oa[kc] = *(const sv8*)(orow + kc * 16);
    }
    f32x16 dacc[4];
#pragma unroll
    for (int ot = 0; ot < 4; ot++)
#pragma unroll
        for (int r = 0; r < 16; r++) dacc[ot][r] = 0.f;
#pragma unroll
    for (int ot = 0; ot < 4; ot++) {
        const unsigned short* brow = pwb + (ot * 32 + lrow) * kC + hi * 8;
#pragma unroll
        for (int kc = 0; kc < 8; kc++)
            dacc[ot] = __builtin_amdgcn_mfma_f32_32x32x16_bf16(
                           oa[kc], *(const sv8*)(brow + kc * 16), dacc[ot], 0, 0, 0);
    }
    // D -> o_lds bf16 [128 n][136 o] (own rows only; reads already in regs)
#pragma unroll
    for (int ot = 0; ot < 4; ot++)
#pragma unroll
        for (int r = 0; r < 16; r++) {
            int n = wave * 32 + (r & 3) + 8 * (r >> 2) + 4 * hi;
            o_lds[n * 136 + ot * 32 + lrow] = f2bf(dacc[ot][r]);
        }
    __syncthreads();
    // epilogue: out[b][o][n0+n] = D[n][o] + proj_b[o] + x  (coalesced)
#pragma unroll 4
    for (int it = 0; it < 64; it++) {
        int idx = it * 256 + tid;
        int o = idx >> 7, n = idx & 127;
        size_t gi = ((size_t)b * kC + o) * kHW + n0 + n;
        out[gi] = bf2f(o_lds[n * 136 + o]) + proj_b[o] + x[gi];
    }
}

extern "C" void kernel_launch(void* const* d_in, const int* in_sizes, int n_in,
                              void* d_out, int out_size, void* d_ws, size_t ws_size,
                              hipStream_t stream) {
    const float* x      = (const float*)d_in[0];
    const float* nd     = (const float*)d_in[1];
    const float* gamma  = (const float*)d_in[2];
    const float* beta   = (const float*)d_in[3];
    const float* q_w    = (const float*)d_in[4];
    const float* q_b    = (const float*)d_in[5];
    const float* nd_w   = (const float*)d_in[6];
    const float* nd_b   = (const float*)d_in[7];
    const float* proj_w = (const float*)d_in[8];
    const float* proj_b = (const float*)d_in[9];
    float* out = (float*)d_out;

    float* stats          = (float*)d_ws;                  // 1024 f32
    unsigned short* pwb   = (unsigned short*)(stats + 1024);       // 16384
    unsigned short* kv_bf = pwb + 16384;                   // 1,048,576
    unsigned short* kvT_bf = kv_bf + (size_t)kB * kL * kC; // 1,048,576
    unsigned short* q_bf  = kvT_bf + (size_t)kB * kL * kC; // 8,388,608

    gn_stats_k<<<dim3(kB * kG), dim3(256), 0, stream>>>(x, stats);
    prep_k<<<dim3(16), dim3(256), 0, stream>>>(proj_w, pwb);
    kv_k<<<dim3(kL / 8, kB), dim3(256), 0, stream>>>(nd, nd_w, nd_b, kv_bf, kvT_bf);
    qproj_k<<<dim3(kHW / 128, kB), dim3(256), 0, stream>>>(x, stats, gamma, beta, q_w, q_b, q_bf);
    attn_k<<<dim3(kHW / 128, kB), dim3(256), 0, stream>>>(q_bf, kv_bf, kvT_bf, pwb,
                                                          proj_b, x, out);
}